// Round 12
// baseline (439.687 us; speedup 1.0000x reference)
//
#include <hip/hip_runtime.h>
#include <math.h>

#define N 256
#define Dd 128

__device__ __forceinline__ double inv2s2_of(int s){
    return (s==0)?0.5:(s==1)?5.0e-3:(s==2)?5.0e-5:5.0e-7;
}

// verified elementwise f64 GJ sweep of a 32x32 LDS tile (rounds 1/4/6/10/11).
// After the loop the swept tile = -D^{-1}; negate so P = D^{-1}.
__device__ __forceinline__ void sweep32(double P[32][33], int tid){
    if (tid < 64){
        int r = tid & 31, cg = tid >> 5;
        for (int j = 0; j < 32; j++){
            double d    = P[j][j];
            double invd = 1.0 / d;
            double cr   = P[r][j];
            double s    = cr * invd;
            bool rj = (r == j);
            double nv[16];
            #pragma unroll
            for (int c = 0; c < 16; c++){
                int col = cg*16 + c;
                double pj = P[j][col];
                double v  = P[r][col];
                nv[c] = rj ? ((col == j) ? -invd : v * invd)
                           : ((col == j) ? s : v - s*pj);
            }
            #pragma unroll
            for (int c = 0; c < 16; c++) P[r][cg*16+c] = nv[c];
        }
        #pragma unroll
        for (int c = 0; c < 16; c++) P[r][cg*16+c] = -P[r][cg*16+c];
    }
}

// ------- fused gather + distances + kernel matrices + bnum partials ---------
// w=0: (z1,z1)+(z2,z2)         -> S0[4..8) (Anum, f64, +lam)
// w=1: (z1,z1[p1])+(z2,z2[p2]) -> bpart[s][row][bx] (16-col partial sums)
// w=2: (z2[p2],z2[p2])         -> S0[0..4) (Aden, f64, +lam)
// w=3: (z2[p2],z2)             -> M4 (f32)
// w=4: (z1,z2)                 -> U4 (f32)
__global__ void k_dist(const float* __restrict__ z1, const float* __restrict__ z2,
                       const int* __restrict__ p1, const int* __restrict__ p2,
                       double* __restrict__ S0, float* __restrict__ M4,
                       float* __restrict__ U4, double* __restrict__ bpart){
    __shared__ float Xs[16][17], Ys[16][17];
    int w = blockIdx.z;
    int tx = threadIdx.x, ty = threadIdx.y;
    int row = blockIdx.y*16 + ty, col = blockIdx.x*16 + tx;
    const float *Xb[2], *Yb[2]; const int *Xp[2], *Yp[2]; int npair = 1;
    Xb[1]=0; Yb[1]=0; Xp[0]=0; Yp[0]=0; Xp[1]=0; Yp[1]=0;
    switch(w){
        case 0: Xb[0]=z1; Yb[0]=z1; Xb[1]=z2; Yb[1]=z2; npair=2; break;
        case 1: Xb[0]=z1; Yb[0]=z1; Yp[0]=p1; Xb[1]=z2; Yb[1]=z2; Yp[1]=p2; npair=2; break;
        case 2: Xb[0]=z2; Yb[0]=z2; Xp[0]=p2; Yp[0]=p2; break;
        case 3: Xb[0]=z2; Yb[0]=z2; Xp[0]=p2; break;
        default:Xb[0]=z1; Yb[0]=z2; break;
    }
    double acc = 0.0;
    for (int p = 0; p < npair; p++){
        const float* X = Xb[p]; const float* Y = Yb[p];
        int xr = blockIdx.y*16 + ty; if (Xp[p]) xr = Xp[p][xr];
        int yr = blockIdx.x*16 + ty; if (Yp[p]) yr = Yp[p][yr];
        for (int c = 0; c < Dd; c += 16){
            __syncthreads();
            Xs[ty][tx] = X[xr*Dd + c + tx];
            Ys[ty][tx] = Y[yr*Dd + c + tx];
            __syncthreads();
            #pragma unroll
            for (int t = 0; t < 16; t++){
                float d = Xs[ty][t] - Ys[tx][t];
                acc += (double)d * (double)d;
            }
        }
    }
    int o = row*N + col;
    if (w == 0){
        #pragma unroll
        for (int s = 0; s < 4; s++){
            double v = exp(-inv2s2_of(s)*acc);
            if (row == col) v += 1.0e-3;
            S0[(size_t)(4+s)*N*N + o] = v;
        }
    } else if (w == 1){
        #pragma unroll
        for (int s = 0; s < 4; s++){
            double v = exp(-inv2s2_of(s)*acc);
            v += __shfl_down(v, 8, 16);
            v += __shfl_down(v, 4, 16);
            v += __shfl_down(v, 2, 16);
            v += __shfl_down(v, 1, 16);
            if (tx == 0) bpart[((size_t)s*N + row)*16 + blockIdx.x] = v;
        }
    } else if (w == 2){
        #pragma unroll
        for (int s = 0; s < 4; s++){
            double v = exp(-inv2s2_of(s)*acc);
            if (row == col) v += 1.0e-3;
            S0[(size_t)s*N*N + o] = v;
        }
    } else if (w == 3){
        #pragma unroll
        for (int s = 0; s < 4; s++) M4[s*N*N + o] = (float)exp(-inv2s2_of(s)*acc);
    } else {
        #pragma unroll
        for (int s = 0; s < 4; s++) U4[s*N*N + o] = (float)exp(-inv2s2_of(s)*acc);
    }
}

// ------ B = M*U^T (f32 in, f64 out); z=4 slice: pivot0 sweep + dsum zero ------
__global__ void k_gemm_nt(const float* __restrict__ M4, const float* __restrict__ U4,
                          double* __restrict__ Bmat, const double* __restrict__ S0,
                          double* __restrict__ Pg0, double* __restrict__ dsum){
    __shared__ float Ms[32][33], Us[32][33];
    __shared__ double P[32][33];
    int tx = threadIdx.x, ty = threadIdx.y;
    int tid = ty*16 + tx;
    if (blockIdx.z == 4){
        if (blockIdx.y != 0) return;
        int mat = blockIdx.x;
        if (mat == 0) dsum[tid] = 0.0;
        const double* S = S0 + (size_t)mat*65536;
        #pragma unroll
        for (int l = 0; l < 4; l++){
            int e = tid + l*256; P[e>>5][e&31] = S[(size_t)(e>>5)*N + (e&31)];
        }
        __syncthreads();
        sweep32(P, tid);
        __syncthreads();
        double* Pp = Pg0 + (size_t)mat*1024;
        #pragma unroll
        for (int l = 0; l < 4; l++){
            int e = tid + l*256; Pp[e] = P[e>>5][e&31];
        }
        return;
    }
    int s = blockIdx.z;
    const float* Mp = M4 + s*N*N;
    const float* Up = U4 + s*N*N;
    double* Bp = Bmat + s*N*N;
    int bj = blockIdx.y*32, bi = blockIdx.x*32;
    double a00=0, a01=0, a10=0, a11=0;
    for (int kc = 0; kc < N; kc += 32){
        __syncthreads();
        #pragma unroll
        for (int l = 0; l < 4; l++){
            int e = tid + l*256; int r = e >> 5, c = e & 31;
            Ms[r][c] = Mp[(bj+r)*N + kc + c];
            Us[r][c] = Up[(bi+r)*N + kc + c];
        }
        __syncthreads();
        #pragma unroll
        for (int k = 0; k < 32; k++){
            float x0 = Ms[2*ty][k], x1 = Ms[2*ty+1][k];
            float y0 = Us[2*tx][k], y1 = Us[2*tx+1][k];
            a00 += (double)x0*y0; a01 += (double)x0*y1;
            a10 += (double)x1*y0; a11 += (double)x1*y1;
        }
    }
    Bp[(bj+2*ty  )*N + bi+2*tx  ] = a00;
    Bp[(bj+2*ty  )*N + bi+2*tx+1] = a01;
    Bp[(bj+2*ty+1)*N + bi+2*tx  ] = a10;
    Bp[(bj+2*ty+1)*N + bi+2*tx+1] = a11;
}

// ====== blocked f64 GJ inversion: ping-pong multi-launch (round-11 algebra) =====
// XCD AFFINITY: 1D grid of 448 blocks, mat = blockIdx.x % 8 (workgroups are
// dispatched round-robin across the 8 XCDs, so all blocks of matrix m land on
// XCD m every step -> S0[m]+S1[m]+Pg[m] (~1MB) stay resident in that XCD's
// 4MB L2 across all 8 steps; round-11's (56,8) grid had 56%8==0 so matrices
// scattered across XCDs -> 8MB HBM round-trip per step (42.5us each).
// task<49: trailing (I,J); task>=49: colrow T. 256 threads.
__global__ void k_step(const double* __restrict__ Ssrc, double* __restrict__ Sdst,
                       const double* __restrict__ PgS, double* __restrict__ PgD, int k){
    __shared__ double Pl[32][33], EJ[32][33], Cl[32][33], El[32][33];
    int b = blockIdx.x;
    int mat = b & 7;          // XCD = blockIdx % 8 (heuristic, speed-only)
    int bx = b >> 3;          // task 0..55
    const double* S = Ssrc + (size_t)mat*65536;
    double* D = Sdst + (size_t)mat*65536;
    const double* Pp = PgS + (size_t)mat*1024;
    int tid = threadIdx.x;
    int Kb = k*32;
    #pragma unroll
    for (int l = 0; l < 4; l++){
        int e = tid + l*256; Pl[e>>5][e&31] = Pp[e];
    }
    if (bx < 49){
        int I = bx / 7, J = bx % 7;
        int GI = ((I < k) ? I : I + 1) * 32;
        int GJ = ((J < k) ? J : J + 1) * 32;
        #pragma unroll
        for (int l = 0; l < 4; l++){
            int e = tid + l*256; int r = e >> 5, c = e & 31;
            El[r][c] = S[(size_t)(GI + r)*N + Kb + c];
            EJ[r][c] = S[(size_t)(GJ + r)*N + Kb + c];
        }
        __syncthreads();
        #pragma unroll
        for (int l = 0; l < 4; l++){
            int e = tid + l*256; int r = e >> 5, c = e & 31;
            double acc = 0.0;
            #pragma unroll
            for (int kk = 0; kk < 32; kk++) acc += EJ[r][kk] * Pl[kk][c];
            Cl[r][c] = acc;
        }
        __syncthreads();
        int pr = tid >> 4, pc = tid & 15;
        int r0 = 2*pr, c0 = 2*pc;
        double a00 = S[(size_t)(GI+r0)*N + GJ+c0];
        double a01 = S[(size_t)(GI+r0)*N + GJ+c0+1];
        double a10 = S[(size_t)(GI+r0+1)*N + GJ+c0];
        double a11 = S[(size_t)(GI+r0+1)*N + GJ+c0+1];
        #pragma unroll
        for (int kk = 0; kk < 32; kk++){
            double e0 = El[r0][kk],   e1 = El[r0+1][kk];
            double b0 = Cl[c0][kk],   b1 = Cl[c0+1][kk];
            a00 -= e0*b0; a01 -= e0*b1;
            a10 -= e1*b0; a11 -= e1*b1;
        }
        double* Dp = D + (size_t)(GI + r0)*N + GJ + c0;
        Dp[0]   = a00; Dp[1]   = a01;
        Dp[N]   = a10; Dp[N+1] = a11;
        // fold next pivot sweep: this block produced dst tile (k+1,k+1)
        if (I == k && J == k && k < 7){
            __syncthreads();
            El[r0][c0]   = a00; El[r0][c0+1]   = a01;
            El[r0+1][c0] = a10; El[r0+1][c0+1] = a11;
            __syncthreads();
            sweep32(El, tid);
            __syncthreads();
            double* Pd = PgD + (size_t)mat*1024;
            #pragma unroll
            for (int l = 0; l < 4; l++){
                int e = tid + l*256; Pd[e] = El[e>>5][e&31];
            }
        }
    } else {
        int T = bx - 49;
        int GT = ((T < k) ? T : T + 1) * 32;
        #pragma unroll
        for (int l = 0; l < 4; l++){
            int e = tid + l*256; int r = e >> 5, c = e & 31;
            El[r][c] = S[(size_t)(GT + r)*N + Kb + c];
        }
        __syncthreads();
        #pragma unroll
        for (int l = 0; l < 4; l++){
            int e = tid + l*256; int r = e >> 5, c = e & 31;
            double acc = 0.0;
            #pragma unroll
            for (int kk = 0; kk < 32; kk++) acc += El[r][kk] * Pl[kk][c];
            Cl[r][c] = acc;
        }
        __syncthreads();
        #pragma unroll
        for (int l = 0; l < 4; l++){
            int e = tid + l*256; int r = e >> 5, c = e & 31;
            D[(size_t)(GT + r)*N + Kb + c] = Cl[r][c];          // col block
        }
        #pragma unroll
        for (int l = 0; l < 4; l++){
            int e = tid + l*256; int cc = e >> 5, rr = e & 31;
            D[(size_t)(Kb + cc)*N + GT + rr] = Cl[rr][cc];      // row block = C^T
        }
        if (T == 0){
            #pragma unroll
            for (int l = 0; l < 4; l++){
                int e = tid + l*256; int i = e >> 5, j = e & 31;
                D[(size_t)(Kb + i)*N + Kb + j] = -Pl[i][j];     // pivot block
            }
        }
    }
}

// ------ X[s] = G[s]*B[s] in f64 (G = -Sfin, no IR needed: err ~ cond*eps64) ------
__global__ void k_x(const double* __restrict__ Sfin, const double* __restrict__ Bmat,
                    float* __restrict__ Xm){
    int s = blockIdx.z;
    const double* Sp = Sfin + (size_t)s*N*N;
    const double* Bp = Bmat + (size_t)s*N*N;
    float* Xp = Xm + (size_t)s*N*N;
    __shared__ double Gs[32][33], Bs[32][33];
    int tx = threadIdx.x, ty = threadIdx.y;
    int tid = ty*16 + tx;
    int bj = blockIdx.y*32, bi = blockIdx.x*32;
    double a00=0, a01=0, a10=0, a11=0;
    for (int kc = 0; kc < N; kc += 32){
        __syncthreads();
        #pragma unroll
        for (int l = 0; l < 4; l++){
            int e = tid + l*256; int r = e >> 5, c = e & 31;
            Gs[r][c] = -Sp[(size_t)(bj+r)*N + kc + c];
            Bs[r][c] = Bp[(size_t)(kc+r)*N + bi + c];
        }
        __syncthreads();
        #pragma unroll
        for (int k = 0; k < 32; k++){
            double x0 = Gs[2*ty][k], x1 = Gs[2*ty+1][k];
            double y0 = Bs[k][2*tx], y1 = Bs[k][2*tx+1];
            a00 += x0*y0; a01 += x0*y1;
            a10 += x1*y0; a11 += x1*y1;
        }
    }
    Xp[(bj+2*ty  )*N + bi+2*tx  ] = (float)a00;
    Xp[(bj+2*ty  )*N + bi+2*tx+1] = (float)a01;
    Xp[(bj+2*ty+1)*N + bi+2*tx  ] = (float)a10;
    Xp[(bj+2*ty+1)*N + bi+2*tx+1] = (float)a11;
}

// ---- b<64: relu(avg over sigma of Xm) column sums -> dsum (f64 atomics).
// ---- b in 64..67: numerator solve rnum[s] = Gnum*b (coalesced via symmetry).
__global__ void k_red(const float* __restrict__ Xm, const double* __restrict__ Sfin,
                      const double* __restrict__ bpart, double* __restrict__ dsum,
                      float* __restrict__ rnum){
    __shared__ double cp[32][33];
    __shared__ double bsh[256];
    int b = blockIdx.x, tid = threadIdx.x;
    if (b < 64){
        int bj = (b >> 3)*32, bi = (b & 7)*32;
        #pragma unroll
        for (int l = 0; l < 4; l++){
            int e = tid + l*256; int r = e >> 5, c = e & 31;
            int o = (bj + r)*N + bi + c;
            float x = Xm[0*N*N + o] + Xm[1*N*N + o] + Xm[2*N*N + o] + Xm[3*N*N + o];
            cp[r][c] = (double)fmaxf(0.25f*x, 0.f);
        }
        __syncthreads();
        if (tid < 32){
            double ssum = 0;
            #pragma unroll
            for (int r = 0; r < 32; r++) ssum += cp[r][tid];
            atomicAdd(&dsum[bi + tid], ssum);
        }
    } else {
        int s = b - 64, j = tid;
        const double* Sn = Sfin + (size_t)(4+s)*N*N;   // Gnum = -Sn (symmetric)
        const double* bp = bpart + (size_t)s*N*16;
        double acc = 0;
        #pragma unroll
        for (int t = 0; t < 16; t++) acc += bp[j*16 + t];
        bsh[j] = acc;
        __syncthreads();
        double y = 0;
        for (int k = 0; k < N; k++) y -= Sn[(size_t)k*N + j] * bsh[k];
        rnum[s*N + j] = (float)y;
    }
}

// ---------------- final loss ----------------
__global__ void k_loss2(const double* __restrict__ dsum, const float* __restrict__ rnum,
                        float* __restrict__ out){
    __shared__ double red[256];
    int i = threadIdx.x;
    double denum = dsum[i] + (double)N * 1.0e-3;
    float ravg = 0.25f*(rnum[0*N+i] + rnum[1*N+i] + rnum[2*N+i] + rnum[3*N+i]);
    double rn = (double)fmaxf(ravg, 0.f) + 1.0e-3;
    red[i] = log(rn) + log(denum);
    __syncthreads();
    for (int st = 128; st > 0; st >>= 1){
        if (i < st) red[i] += red[i + st];
        __syncthreads();
    }
    if (i == 0) out[0] = (float)red[0];
}

extern "C" void kernel_launch(void* const* d_in, const int* in_sizes, int n_in,
                              void* d_out, int out_size, void* d_ws, size_t ws_size,
                              hipStream_t stream) {
    (void)in_sizes; (void)n_in; (void)out_size; (void)ws_size;
    const float* z1 = (const float*)d_in[0];
    const float* z2 = (const float*)d_in[1];
    const int*   p1 = (const int*)d_in[2];
    const int*   p2 = (const int*)d_in[3];
    float* out = (float*)d_out;

    char* w = (char*)d_ws;
    size_t o = 0;
    auto carve = [&](size_t bytes) -> char* {
        char* p = w + o;
        o += (bytes + 255) & ~(size_t)255;
        return p;
    };
    double* bpart = (double*)carve((size_t)4*N*16*sizeof(double));
    double* dsum  = (double*)carve((size_t)N*sizeof(double));
    float*  M4    = (float*) carve((size_t)4*N*N*sizeof(float));
    float*  U4    = (float*) carve((size_t)4*N*N*sizeof(float));
    double* Bmat  = (double*)carve((size_t)4*N*N*sizeof(double));
    float*  Xm    = (float*) carve((size_t)4*N*N*sizeof(float));
    float*  rnum  = (float*) carve((size_t)4*N*sizeof(float));
    double* S0    = (double*)carve((size_t)8*N*N*sizeof(double));  // ping
    double* S1    = (double*)carve((size_t)8*N*N*sizeof(double));  // pong
    double* Pg0   = (double*)carve((size_t)8*32*32*sizeof(double));
    double* Pg1   = (double*)carve((size_t)8*32*32*sizeof(double));

    k_dist<<<dim3(16,16,5), dim3(16,16), 0, stream>>>(z1, z2, p1, p2,
                                                      S0, M4, U4, bpart);
    k_gemm_nt<<<dim3(8,8,5), dim3(16,16), 0, stream>>>(M4, U4, Bmat, S0, Pg0, dsum);
    for (int k = 0; k < 8; k++){
        double* src = (k & 1) ? S1 : S0;
        double* dst = (k & 1) ? S0 : S1;
        double* ps  = (k & 1) ? Pg1 : Pg0;
        double* pd  = (k & 1) ? Pg0 : Pg1;
        k_step<<<dim3(448), dim3(256), 0, stream>>>(src, dst, ps, pd, k);
    }
    // after k=7 (odd): final swept matrices in S0
    k_x<<<dim3(8,8,4), dim3(16,16), 0, stream>>>(S0, Bmat, Xm);
    k_red<<<dim3(68), dim3(256), 0, stream>>>(Xm, S0, bpart, dsum, rnum);
    k_loss2<<<dim3(1), dim3(256), 0, stream>>>(dsum, rnum, out);
}